// Round 8
// baseline (376.974 us; speedup 1.0000x reference)
//
#include <hip/hip_runtime.h>
#include <hip/hip_bf16.h>

// Problem constants (B,T,S,D = 32,1024,1024,512)
#define B_ 32
#define T_ 1024
#define S_ 1024
#define D_ 512
#define M_ (B_*T_)       // 32768 GEMM rows
#define N_ D_            // 512  GEMM cols
#define K_ (2*D_)        // 1024 GEMM reduction

typedef __attribute__((ext_vector_type(8))) short bf16x8;  // 8 bf16 = 4 VGPRs
typedef __attribute__((ext_vector_type(4))) float f32x4;

__device__ inline unsigned short f2bf(float x) {
    union { float f; unsigned u; } v; v.f = x;
    unsigned r = v.u + 0x7FFFu + ((v.u >> 16) & 1u);   // RNE
    return (unsigned short)(r >> 16);
}

// pack 2 f32 -> 2 bf16 (RNE), packed in 32 bits
__device__ inline unsigned cvt2bf(float lo, float hi) {
#if __has_builtin(__builtin_amdgcn_cvt_pk_bf16_f32)
    typedef __attribute__((ext_vector_type(2))) __bf16 bf2;
    union { bf2 v; unsigned u; } r;
    r.v = __builtin_amdgcn_cvt_pk_bf16_f32(lo, hi);
    return r.u;
#else
    return (unsigned)f2bf(lo) | ((unsigned)f2bf(hi) << 16);
#endif
}

// fast tanh: 1 - 2/(e^{2x}+1) via hw exp2 + rcp. rel err ~1e-7, exact sat at +-1.
__device__ inline float fast_tanh(float x) {
#if __has_builtin(__builtin_amdgcn_exp2f) && __has_builtin(__builtin_amdgcn_rcpf)
    const float e = __builtin_amdgcn_exp2f(x * 2.885390082f);   // e^{2x}
    const float r = __builtin_amdgcn_rcpf(e + 1.0f);
    return 1.0f - 2.0f * r;
#else
    return tanhf(x);
#endif
}

// ---------------------------------------------------------------------------
// Kernel 1: alignment scan -> jbuf.
// ---------------------------------------------------------------------------
__global__ void align_kernel(const int* __restrict__ iv, int* __restrict__ jbuf) {
    const int b = blockIdx.x;          // 32 blocks x 64 threads
    const int lane = threadIdx.x;      // 16 tokens per lane
    const int* row = iv + b * T_;
    int f[16];
    int local = 0;
    const int t0 = lane * 16;
    #pragma unroll
    for (int q = 0; q < 16; ++q) {
        const int t = t0 + q;
        const int tok = row[t];
        const int fl = (t > 0 && (tok == 1 || tok == 2)) ? 1 : 0;
        f[q] = fl;
        local += fl;
    }
    int incl = local;
    #pragma unroll
    for (int off = 1; off < 64; off <<= 1) {
        const int up = __shfl_up(incl, off, 64);
        if (lane >= off) incl += up;
    }
    int run = incl - local;            // exclusive prefix at this lane's first token
    #pragma unroll
    for (int q = 0; q < 16; ++q) {
        const int t = t0 + q;
        run += f[q];
        int j;
        if (t == 0) {
            j = 0;                     // attn[b,0,0] = 1 always
        } else {
            j = t - run - 1;
            if (j < 0) j += S_;        // torch negative-index wrap
        }
        jbuf[b * T_ + t] = j;
    }
}

// ---------------------------------------------------------------------------
// Kernel 2: W [512,1024] f32 -> bf16
// ---------------------------------------------------------------------------
__global__ void pack_w(const float* __restrict__ W, unsigned short* __restrict__ Wbf) {
    const int idx = blockIdx.x * blockDim.x + threadIdx.x;   // N_*K_/8 threads
    const f32x4 a = ((const f32x4*)W)[idx * 2];
    const f32x4 c = ((const f32x4*)W)[idx * 2 + 1];
    union { bf16x8 v; unsigned u[4]; } pk;
    pk.u[0] = cvt2bf(a[0], a[1]); pk.u[1] = cvt2bf(a[2], a[3]);
    pk.u[2] = cvt2bf(c[0], c[1]); pk.u[3] = cvt2bf(c[2], c[3]);
    *(bf16x8*)(Wbf + (size_t)idx * 8) = pk.v;
}

// ---------------------------------------------------------------------------
// Kernel 3: prep — fused gather+convert of the GEMM A-matrix.
// Abf[m][0:512]    = bf16(ctx[m>>10, jbuf[m], :])  (gathered row, L3-hot)
// Abf[m][512:1024] = bf16(outp[m, :])
// Pure streaming: per row read 4 KB / write 2 KB, fully coalesced.
// Abf lives in the attn region of d_out (scratch; attn_fill overwrites LAST).
// ---------------------------------------------------------------------------
__global__ __launch_bounds__(256)
void prep_kernel(const float* __restrict__ ctx, const float* __restrict__ outp,
                 const int* __restrict__ jbuf, unsigned short* __restrict__ Abf) {
    const int bx = blockIdx.x;                 // 1024 blocks x 32 rows
    const int wave = threadIdx.x >> 6;
    const int lane = threadIdx.x & 63;
    #pragma unroll 2
    for (int r = 0; r < 8; ++r) {
        const int m = bx * 32 + wave * 8 + r;
        const int j = jbuf[m];
        const int b = m >> 10;
        const float* s1 = ctx + ((size_t)(b * S_ + j)) * D_ + lane * 8;
        const float* s2 = outp + (size_t)m * D_ + lane * 8;
        const f32x4 a0 = ((const f32x4*)s1)[0];
        const f32x4 a1 = ((const f32x4*)s1)[1];
        const f32x4 c0 = ((const f32x4*)s2)[0];
        const f32x4 c1 = ((const f32x4*)s2)[1];
        union { bf16x8 v; unsigned u[4]; } p1, p2;
        p1.u[0] = cvt2bf(a0[0], a0[1]); p1.u[1] = cvt2bf(a0[2], a0[3]);
        p1.u[2] = cvt2bf(a1[0], a1[1]); p1.u[3] = cvt2bf(a1[2], a1[3]);
        p2.u[0] = cvt2bf(c0[0], c0[1]); p2.u[1] = cvt2bf(c0[2], c0[3]);
        p2.u[2] = cvt2bf(c1[0], c1[1]); p2.u[3] = cvt2bf(c1[2], c1[3]);
        *(bf16x8*)(Abf + (size_t)m * K_ + lane * 8)       = p1.v;
        *(bf16x8*)(Abf + (size_t)m * K_ + D_ + lane * 8)  = p2.v;
    }
}

// ---------------------------------------------------------------------------
// Kernel 4: pure linear bf16 GEMM (m97-structure): A = Abf [M][K] bf16,
// B = Wbf [N][K] bf16, out = tanh(A·B^T + bias) fp32.
// BOTH operands staged via global_load_lds with pre-swizzled per-lane source
// (granule g of row r lands at LDS slot r*8 + (g ^ (r&7))); no register
// staging, no cvt in the K-loop. Regs ~110 -> (256,4) no-spill, LDS 32 KB
// -> 4 blocks/CU. R5's full-drain 2-barrier loop (traffic-proven) + R9's
// sibling-adjacent same-XCD map (FETCH-floor-proven).
// ---------------------------------------------------------------------------
#define BM 128
#define BN 128
#define BK 64
#define NGEMM ((M_ / BM) * (N_ / BN))    // 1024
#define NATTN 512

__global__ __launch_bounds__(256, 4)
void gemm_lin(const unsigned short* __restrict__ Abf,
              const unsigned short* __restrict__ Wbf,
              const float* __restrict__ bias,
              float* __restrict__ out) {
    __shared__ unsigned short As[BM * BK];   // 16 KB
    __shared__ unsigned short Bs[BN * BK];   // 16 KB

    const int gbx = blockIdx.x;
    const int tid = threadIdx.x;
    const int lane = tid & 63;
    const int wave = tid >> 6;
    const int wm = wave >> 1, wn = wave & 1;     // 2x2 waves -> 64x64 each
    const int l16 = lane & 15, quad = lane >> 4;

    // sibling-adjacent same-XCD map: 4 bn-siblings of each bm spaced 8 apart.
    const int xcd = gbx & 7;
    const int bn  = (gbx >> 3) & 3;              // 4 n-tiles of 128
    const int bm  = ((gbx >> 5) << 3) | xcd;     // 256 m-tiles of 128
    const int mBase = bm * BM;
    const int nBase = bn * BN;

    // DMA source bases: chunk = it*256+tid, row = chunk>>3, granule g = chunk&7;
    // source granule = g ^ (row&7)  (pre-swizzled so the linear LDS dest holds
    // the swizzled layout the MFMA-phase reads expect).
    const unsigned short* aSrc[4];
    const unsigned short* bSrc[4];
    #pragma unroll
    for (int it = 0; it < 4; ++it) {
        const int chunk = it * 256 + tid;
        const int row = chunk >> 3;
        const int g   = chunk & 7;
        const int gk8 = (g ^ (row & 7)) * 8;
        aSrc[it] = Abf + (size_t)(mBase + row) * K_ + gk8;
        bSrc[it] = Wbf + (size_t)(nBase + row) * K_ + gk8;
    }

    f32x4 acc[4][4] = {};

    for (int ko = 0; ko < K_; ko += BK) {
        // ---- stage both tiles via DMA (8 x global_load_lds, no VGPR path)
        #pragma unroll
        for (int it = 0; it < 4; ++it) {
            const int chunk = it * 256 + tid;
            __builtin_amdgcn_global_load_lds(
                (const __attribute__((address_space(1))) void*)(aSrc[it] + ko),
                (__attribute__((address_space(3))) void*)(As + chunk * 8), 16, 0, 0);
        }
        #pragma unroll
        for (int it = 0; it < 4; ++it) {
            const int chunk = it * 256 + tid;
            __builtin_amdgcn_global_load_lds(
                (const __attribute__((address_space(1))) void*)(bSrc[it] + ko),
                (__attribute__((address_space(3))) void*)(Bs + chunk * 8), 16, 0, 0);
        }
        __syncthreads();                       // drain DMAs (convoy anchor)

        // ---- MFMA phase: 2 K-steps of 32; 16 MFMA each
        #pragma unroll
        for (int ks = 0; ks < 2; ++ks) {
            bf16x8 af[4], bfr[4];
            #pragma unroll
            for (int mt = 0; mt < 4; ++mt) {
                const int r = wm * 64 + mt * 16 + l16;
                const int q = ks * 4 + quad;
                af[mt] = *(const bf16x8*)&As[(r * 8 + (q ^ (r & 7))) * 8];
            }
            #pragma unroll
            for (int nt = 0; nt < 4; ++nt) {
                const int r = wn * 64 + nt * 16 + l16;
                const int q = ks * 4 + quad;
                bfr[nt] = *(const bf16x8*)&Bs[(r * 8 + (q ^ (r & 7))) * 8];
            }
            #pragma unroll
            for (int mt = 0; mt < 4; ++mt)
                #pragma unroll
                for (int nt = 0; nt < 4; ++nt)
                    acc[mt][nt] = __builtin_amdgcn_mfma_f32_16x16x32_bf16(
                        af[mt], bfr[nt], acc[mt][nt], 0, 0, 0);
        }
        __syncthreads();
    }

    // ---- epilogue: fast_tanh(acc + bias), fp32 store
    #pragma unroll
    for (int nt = 0; nt < 4; ++nt) {
        const int n = nBase + wn * 64 + nt * 16 + l16;
        const float bv = bias[n];
        #pragma unroll
        for (int mt = 0; mt < 4; ++mt) {
            #pragma unroll
            for (int r = 0; r < 4; ++r) {
                const int m = mBase + wm * 64 + mt * 16 + quad * 4 + r;
                out[(size_t)m * N_ + n] = fast_tanh(acc[mt][nt][r] + bv);
            }
        }
    }
}

// ---------------------------------------------------------------------------
// Kernel 5: attn one-hot fill (R5's proven streaming writer), runs LAST —
// overwrites the Abf scratch that aliases the attn region.
// ---------------------------------------------------------------------------
__global__ __launch_bounds__(256)
void attn_fill(float* __restrict__ attn, const int* __restrict__ jbuf) {
    const int bx = blockIdx.x;             // 512 blocks x 64 rows
    const int tid = threadIdx.x;
    const int m0 = bx * 64;
    #pragma unroll 4
    for (int r = 0; r < 64; ++r) {
        const int row = m0 + r;
        const int j = jbuf[row];           // broadcast load
        f32x4 v = {0.f, 0.f, 0.f, 0.f};
        if ((j >> 2) == tid) v[j & 3] = 1.0f;
        ((f32x4*)(attn + (size_t)row * S_))[tid] = v;
    }
}

// ---------------------------------------------------------------------------
extern "C" void kernel_launch(void* const* d_in, const int* in_sizes, int n_in,
                              void* d_out, int out_size, void* d_ws, size_t ws_size,
                              hipStream_t stream) {
    const int*   iv   = (const int*)d_in[0];    // input_var [B,T]
    const float* outp = (const float*)d_in[1];  // output   [B,T,D]
    const float* ctx  = (const float*)d_in[2];  // context  [B,S,D]
    // d_in[3] = di (unused by reference body)
    const float* W    = (const float*)d_in[4];  // [D, 2D]
    const float* bias = (const float*)d_in[5];  // [D]

    float* out  = (float*)d_out;                       // [B,T,D]
    float* attn = out + (size_t)M_ * N_;               // [B,T,S]

    // workspace layout: j[M_] int32 | Wbf[N_*K_] bf16   (~1.1 MB total)
    int* jbuf = (int*)d_ws;
    unsigned short* Wbf = (unsigned short*)((char*)d_ws + (size_t)M_ * 4);

    // Abf scratch (64 MB) aliases the attn region (128 MB); attn_fill runs
    // last and overwrites it (stream-serialized -> safe, no ws_size needed).
    unsigned short* Abf = (unsigned short*)attn;

    align_kernel<<<B_, 64, 0, stream>>>(iv, jbuf);
    pack_w<<<(N_ * K_ / 8) / 256, 256, 0, stream>>>(W, Wbf);
    prep_kernel<<<M_ / 32, 256, 0, stream>>>(ctx, outp, jbuf, Abf);
    gemm_lin<<<NGEMM, 256, 0, stream>>>(Abf, Wbf, bias, out);
    attn_fill<<<NATTN, 256, 0, stream>>>(attn, jbuf);
}

// Round 9
// 329.930 us; speedup vs baseline: 1.1426x; 1.1426x over previous
//
#include <hip/hip_runtime.h>
#include <hip/hip_bf16.h>

// Problem constants (B,T,S,D = 32,1024,1024,512)
#define B_ 32
#define T_ 1024
#define S_ 1024
#define D_ 512
#define M_ (B_*T_)       // 32768 GEMM rows
#define N_ D_            // 512  GEMM cols
#define K_ (2*D_)        // 1024 GEMM reduction

typedef __attribute__((ext_vector_type(8))) short bf16x8;  // 8 bf16 = 4 VGPRs
typedef __attribute__((ext_vector_type(4))) float f32x4;

__device__ inline unsigned short f2bf(float x) {
    union { float f; unsigned u; } v; v.f = x;
    unsigned r = v.u + 0x7FFFu + ((v.u >> 16) & 1u);   // RNE
    return (unsigned short)(r >> 16);
}

// pack 2 f32 -> 2 bf16 (RNE), packed in 32 bits
__device__ inline unsigned cvt2bf(float lo, float hi) {
#if __has_builtin(__builtin_amdgcn_cvt_pk_bf16_f32)
    typedef __attribute__((ext_vector_type(2))) __bf16 bf2;
    union { bf2 v; unsigned u; } r;
    r.v = __builtin_amdgcn_cvt_pk_bf16_f32(lo, hi);
    return r.u;
#else
    return (unsigned)f2bf(lo) | ((unsigned)f2bf(hi) << 16);
#endif
}

// fast tanh: 1 - 2/(e^{2x}+1) via hw exp2 + rcp. rel err ~1e-7, exact sat at +-1.
__device__ inline float fast_tanh(float x) {
#if __has_builtin(__builtin_amdgcn_exp2f) && __has_builtin(__builtin_amdgcn_rcpf)
    const float e = __builtin_amdgcn_exp2f(x * 2.885390082f);   // e^{2x}
    const float r = __builtin_amdgcn_rcpf(e + 1.0f);
    return 1.0f - 2.0f * r;
#else
    return tanhf(x);
#endif
}

// ---------------------------------------------------------------------------
// Kernel 1: alignment scan -> jbuf.
// ---------------------------------------------------------------------------
__global__ void align_kernel(const int* __restrict__ iv, int* __restrict__ jbuf) {
    const int b = blockIdx.x;          // 32 blocks x 64 threads
    const int lane = threadIdx.x;      // 16 tokens per lane
    const int* row = iv + b * T_;
    int f[16];
    int local = 0;
    const int t0 = lane * 16;
    #pragma unroll
    for (int q = 0; q < 16; ++q) {
        const int t = t0 + q;
        const int tok = row[t];
        const int fl = (t > 0 && (tok == 1 || tok == 2)) ? 1 : 0;
        f[q] = fl;
        local += fl;
    }
    int incl = local;
    #pragma unroll
    for (int off = 1; off < 64; off <<= 1) {
        const int up = __shfl_up(incl, off, 64);
        if (lane >= off) incl += up;
    }
    int run = incl - local;            // exclusive prefix at this lane's first token
    #pragma unroll
    for (int q = 0; q < 16; ++q) {
        const int t = t0 + q;
        run += f[q];
        int j;
        if (t == 0) {
            j = 0;                     // attn[b,0,0] = 1 always
        } else {
            j = t - run - 1;
            if (j < 0) j += S_;        // torch negative-index wrap
        }
        jbuf[b * T_ + t] = j;
    }
}

// ---------------------------------------------------------------------------
// Kernel 2: W [512,1024] f32 -> bf16
// ---------------------------------------------------------------------------
__global__ void pack_w(const float* __restrict__ W, unsigned short* __restrict__ Wbf) {
    const int idx = blockIdx.x * blockDim.x + threadIdx.x;   // N_*K_/8 threads
    const f32x4 a = ((const f32x4*)W)[idx * 2];
    const f32x4 c = ((const f32x4*)W)[idx * 2 + 1];
    union { bf16x8 v; unsigned u[4]; } pk;
    pk.u[0] = cvt2bf(a[0], a[1]); pk.u[1] = cvt2bf(a[2], a[3]);
    pk.u[2] = cvt2bf(c[0], c[1]); pk.u[3] = cvt2bf(c[2], c[3]);
    *(bf16x8*)(Wbf + (size_t)idx * 8) = pk.v;
}

// ---------------------------------------------------------------------------
// Kernel 3 (heterogeneous): blocks [0,256) = GEMM tiles 256x256 (dispatched
// FIRST: each CU immediately gets its gemm block); [256, 768) = attn one-hot
// (co-resident: 8 gemm waves ~230regs + 8 attn waves ~24regs ~ 2032 <= 2048).
//
// R14 = R11's proven loop skeleton scaled to BM=BN=256, BK=64, 512 threads:
//   DMA_B(i)        // 4 global_load_lds (pre-swizzled src, linear dest)
//   STAGE_A(i)      // cvt fa (prefetched last iter) -> swizzled ds_write
//   __syncthreads() // drain B DMA + ds_writes (convoy anchor)
//   LOAD_A(i+1)     // 8 f32x4 -> fa; flies under the 64-MFMA phase (~640cy)
//   MFMA_PH()       // 2 ks x 4 mt x 8 nt; af[4], bfr[8]; acc[4][8]
//   __syncthreads() // drain A prefetch (mostly complete)
// Why: per-unit-work LDS traffic 96->64 KB, 4x barrier amortization,
// full-phase A flight. Occupancy 8 waves/CU (reg-bound) - acceptable per
// m201's 256^2 reference (1 block/CU).
// Sibling-XCD map: bn-pair of each bm 8 slots apart (same XCD).
// ---------------------------------------------------------------------------
#define BM 256
#define BN 256
#define BK 64
#define KMAX (K_ - BK)                   // 960
#define NGEMM ((M_ / BM) * (N_ / BN))    // 128*2 = 256
#define NATTN 512                        // 64 rows each

__global__ __launch_bounds__(512, 2)
void gemm_attn(const unsigned short* __restrict__ Wbf,
               const float* __restrict__ bias,
               float* __restrict__ out,
               float* __restrict__ attn,
               const float* __restrict__ ctx,
               const float* __restrict__ outp,
               const int* __restrict__ jbuf) {
    const int bx = blockIdx.x;
    const int tid = threadIdx.x;

    __shared__ unsigned short As[BM * BK];   // 32 KB
    __shared__ unsigned short Bs[BN * BK];   // 32 KB

    if (bx >= NGEMM) {
        // ---------------- attn one-hot: 64 rows per block, 512 threads ----
        const int m0 = (bx - NGEMM) * 64;
        const int col  = tid & 255;            // f32x4 column (256 per row)
        const int half = tid >> 8;             // 0..1: row parity
        #pragma unroll 4
        for (int r = 0; r < 32; ++r) {
            const int row = m0 + r * 2 + half;
            const int j = jbuf[row];           // wave-uniform broadcast
            f32x4 v = {0.f, 0.f, 0.f, 0.f};
            if ((j >> 2) == col) v[j & 3] = 1.0f;
            ((f32x4*)(attn + (size_t)row * S_))[col] = v;
        }
        return;
    }

    // ---------------- GEMM tile 256x256 ----------------
    const int lane = tid & 63;
    const int wave = tid >> 6;                   // 0..7
    const int wm = wave >> 1, wn = wave & 1;     // 4x2 waves -> 64x128 each
    const int l16 = lane & 15, quad = lane >> 4;

    // sibling-adjacent same-XCD map: bn-pair of each bm spaced 8 apart.
    const int xcd = bx & 7;
    const int bn  = (bx >> 3) & 1;               // 2 n-tiles of 256
    const int bm  = ((bx >> 4) << 3) | xcd;      // 128 m-tiles of 256
    const int mBase = bm * BM;
    const int nBase = bn * BN;

    // A staging: chunk c = it*512+tid, row = it*64 + (tid>>3), g = tid&7.
    const int g    = tid & 7;
    const int rsub = tid >> 3;                   // 0..63
    const int sw   = g ^ (rsub & 7);             // swizzle, it-invariant (64%8==0)
    const float* actx[4];
    const float* aout[4];
    const unsigned short* bSrc[4];
    #pragma unroll
    for (int it = 0; it < 4; ++it) {
        const int r = it * 64 + rsub;
        const int m = mBase + r;
        const int jm = jbuf[m];
        actx[it] = ctx + ((size_t)((m >> 10) * S_ + jm)) * D_ + g * 8;
        aout[it] = outp + (size_t)m * D_ - D_ + g * 8;      // add ko>=512
        // B: row&7 == rsub&7 -> source granule == sw (pre-swizzled, linear dest)
        bSrc[it] = Wbf + (size_t)(nBase + r) * K_ + sw * 8;
    }

    f32x4 acc[4][8] = {};
    f32x4 fa[4][2];

#define LOAD_A(KO) do {                                                        \
    const int _koa = (KO);                                                     \
    _Pragma("unroll")                                                          \
    for (int _it = 0; _it < 4; ++_it) {                                        \
        const float* _src = (_koa < D_) ? (actx[_it] + _koa) : (aout[_it] + _koa); \
        fa[_it][0] = ((const f32x4*)_src)[0];                                  \
        fa[_it][1] = ((const f32x4*)_src)[1];                                  \
    }                                                                          \
} while (0)

    // prologue: prefetch A(0); only iter-0's cvt sees full load latency.
    LOAD_A(0);

    for (int ko = 0; ko < K_; ko += BK) {
        // ---- 1. B(i) -> LDS DMA (4 x global_load_lds, in flight across cvt)
        #pragma unroll
        for (int it = 0; it < 4; ++it) {
            __builtin_amdgcn_global_load_lds(
                (const __attribute__((address_space(1))) void*)(bSrc[it] + ko),
                (__attribute__((address_space(3))) void*)(Bs + (it * 512 + tid) * 8),
                16, 0, 0);
        }
        // ---- 2. cvt + swizzled ds_write_b128 (fa prefetched last iter)
        #pragma unroll
        for (int it = 0; it < 4; ++it) {
            union { bf16x8 v; unsigned u[4]; } pk;
            pk.u[0] = cvt2bf(fa[it][0][0], fa[it][0][1]);
            pk.u[1] = cvt2bf(fa[it][0][2], fa[it][0][3]);
            pk.u[2] = cvt2bf(fa[it][1][0], fa[it][1][1]);
            pk.u[3] = cvt2bf(fa[it][1][2], fa[it][1][3]);
            *(bf16x8*)&As[(it * 512 + rsub * 8 + sw) * 8] = pk.v;
        }
        __syncthreads();                         // drain B DMA + ds_writes

        // ---- 3. prefetch A(i+1) into the same regs; flies under MFMA
        {
            const int ko2 = (ko + BK > KMAX) ? KMAX : ko + BK;   // clamped tail
            LOAD_A(ko2);
        }

        // ---- 4. MFMA phase: 2 K-steps of 32; 32 MFMA each (4mt x 8nt)
        #pragma unroll
        for (int ks = 0; ks < 2; ++ks) {
            bf16x8 af[4], bfr[8];
            const int q = ks * 4 + quad;
            #pragma unroll
            for (int mt = 0; mt < 4; ++mt) {
                const int r = wm * 64 + mt * 16 + l16;
                af[mt] = *(const bf16x8*)&As[(r * 8 + (q ^ (r & 7))) * 8];
            }
            #pragma unroll
            for (int nt = 0; nt < 8; ++nt) {
                const int rb = wn * 128 + nt * 16 + l16;
                bfr[nt] = *(const bf16x8*)&Bs[(rb * 8 + (q ^ (rb & 7))) * 8];
            }
            #pragma unroll
            for (int mt = 0; mt < 4; ++mt)
                #pragma unroll
                for (int nt = 0; nt < 8; ++nt)
                    acc[mt][nt] = __builtin_amdgcn_mfma_f32_16x16x32_bf16(
                        af[mt], bfr[nt], acc[mt][nt], 0, 0, 0);
        }
        __syncthreads();                         // drain A prefetch (mostly done)
    }

#undef LOAD_A

    // ---- epilogue: fast_tanh(acc + bias), fp32 store
    #pragma unroll
    for (int nt = 0; nt < 8; ++nt) {
        const int n = nBase + wn * 128 + nt * 16 + l16;
        const float bv = bias[n];
        #pragma unroll
        for (int mt = 0; mt < 4; ++mt) {
            #pragma unroll
            for (int r = 0; r < 4; ++r) {
                const int m = mBase + wm * 64 + mt * 16 + quad * 4 + r;
                out[(size_t)m * N_ + n] = fast_tanh(acc[mt][nt][r] + bv);
            }
        }
    }
}

// ---------------------------------------------------------------------------
extern "C" void kernel_launch(void* const* d_in, const int* in_sizes, int n_in,
                              void* d_out, int out_size, void* d_ws, size_t ws_size,
                              hipStream_t stream) {
    const int*   iv   = (const int*)d_in[0];    // input_var [B,T]
    const float* outp = (const float*)d_in[1];  // output   [B,T,D]
    const float* ctx  = (const float*)d_in[2];  // context  [B,S,D]
    // d_in[3] = di (unused by reference body)
    const float* W    = (const float*)d_in[4];  // [D, 2D]
    const float* bias = (const float*)d_in[5];  // [D]

    float* out  = (float*)d_out;                       // [B,T,D]
    float* attn = out + (size_t)M_ * N_;               // [B,T,S]

    // workspace layout: j[M_] int32 | Wbf[N_*K_] bf16   (~1.1 MB total)
    int* jbuf = (int*)d_ws;
    unsigned short* Wbf = (unsigned short*)((char*)d_ws + (size_t)M_ * 4);

    align_kernel<<<B_, 64, 0, stream>>>(iv, jbuf);
    pack_w<<<(N_ * K_ / 8) / 256, 256, 0, stream>>>(W, Wbf);
    gemm_attn<<<NGEMM + NATTN, 512, 0, stream>>>(Wbf, bias, out, attn, ctx, outp, jbuf);
}

// Round 10
// 328.241 us; speedup vs baseline: 1.1485x; 1.0051x over previous
//
#include <hip/hip_runtime.h>
#include <hip/hip_bf16.h>

// Problem constants (B,T,S,D = 32,1024,1024,512)
#define B_ 32
#define T_ 1024
#define S_ 1024
#define D_ 512
#define M_ (B_*T_)       // 32768 GEMM rows
#define N_ D_            // 512  GEMM cols
#define K_ (2*D_)        // 1024 GEMM reduction

typedef __attribute__((ext_vector_type(8))) short bf16x8;  // 8 bf16 = 4 VGPRs
typedef __attribute__((ext_vector_type(4))) float f32x4;

__device__ inline unsigned short f2bf(float x) {
    union { float f; unsigned u; } v; v.f = x;
    unsigned r = v.u + 0x7FFFu + ((v.u >> 16) & 1u);   // RNE
    return (unsigned short)(r >> 16);
}

// pack 2 f32 -> 2 bf16 (RNE), packed in 32 bits
__device__ inline unsigned cvt2bf(float lo, float hi) {
#if __has_builtin(__builtin_amdgcn_cvt_pk_bf16_f32)
    typedef __attribute__((ext_vector_type(2))) __bf16 bf2;
    union { bf2 v; unsigned u; } r;
    r.v = __builtin_amdgcn_cvt_pk_bf16_f32(lo, hi);
    return r.u;
#else
    return (unsigned)f2bf(lo) | ((unsigned)f2bf(hi) << 16);
#endif
}

// fast tanh: 1 - 2/(e^{2x}+1) via hw exp2 + rcp. rel err ~1e-7, exact sat at +-1.
__device__ inline float fast_tanh(float x) {
#if __has_builtin(__builtin_amdgcn_exp2f) && __has_builtin(__builtin_amdgcn_rcpf)
    const float e = __builtin_amdgcn_exp2f(x * 2.885390082f);   // e^{2x}
    const float r = __builtin_amdgcn_rcpf(e + 1.0f);
    return 1.0f - 2.0f * r;
#else
    return tanhf(x);
#endif
}

// ---------------------------------------------------------------------------
// Kernel 1: alignment scan -> jbuf.
// ---------------------------------------------------------------------------
__global__ void align_kernel(const int* __restrict__ iv, int* __restrict__ jbuf) {
    const int b = blockIdx.x;          // 32 blocks x 64 threads
    const int lane = threadIdx.x;      // 16 tokens per lane
    const int* row = iv + b * T_;
    int f[16];
    int local = 0;
    const int t0 = lane * 16;
    #pragma unroll
    for (int q = 0; q < 16; ++q) {
        const int t = t0 + q;
        const int tok = row[t];
        const int fl = (t > 0 && (tok == 1 || tok == 2)) ? 1 : 0;
        f[q] = fl;
        local += fl;
    }
    int incl = local;
    #pragma unroll
    for (int off = 1; off < 64; off <<= 1) {
        const int up = __shfl_up(incl, off, 64);
        if (lane >= off) incl += up;
    }
    int run = incl - local;            // exclusive prefix at this lane's first token
    #pragma unroll
    for (int q = 0; q < 16; ++q) {
        const int t = t0 + q;
        run += f[q];
        int j;
        if (t == 0) {
            j = 0;                     // attn[b,0,0] = 1 always
        } else {
            j = t - run - 1;
            if (j < 0) j += S_;        // torch negative-index wrap
        }
        jbuf[b * T_ + t] = j;
    }
}

// ---------------------------------------------------------------------------
// Kernel 2: W [512,1024] f32 -> bf16
// ---------------------------------------------------------------------------
__global__ void pack_w(const float* __restrict__ W, unsigned short* __restrict__ Wbf) {
    const int idx = blockIdx.x * blockDim.x + threadIdx.x;   // N_*K_/8 threads
    const f32x4 a = ((const f32x4*)W)[idx * 2];
    const f32x4 c = ((const f32x4*)W)[idx * 2 + 1];
    union { bf16x8 v; unsigned u[4]; } pk;
    pk.u[0] = cvt2bf(a[0], a[1]); pk.u[1] = cvt2bf(a[2], a[3]);
    pk.u[2] = cvt2bf(c[0], c[1]); pk.u[3] = cvt2bf(c[2], c[3]);
    *(bf16x8*)(Wbf + (size_t)idx * 8) = pk.v;
}

// ---------------------------------------------------------------------------
// Kernel 3 (heterogeneous): blocks [0,256) = GEMM tiles 256x256 (dispatched
// FIRST); [256, 768) = attn one-hot (co-resident: LDS 64KB gemm + 64KB attn
// = 128 <= 160KB/CU; regs 8 gemm waves ~230 + 8 attn waves ~24 ~= 2032).
//
// R15 = R14 (proven 256^2 anchor loop) + NONTEMPORAL streaming stores:
// attn (128 MB) and out (64 MB) have zero reuse; NT bypasses L2 so the
// GEMM working set (A panels + Wbf, ~2 MB/XCD) stays L2-resident instead
// of being evicted by 192 MB of write streaming. (R7's NT regression was
// the counted-vmcnt drift structure, isolated by R8 - not NT itself; R6
// had NT out-stores with clean write traffic.)
//
// K-loop per iter (R14 verbatim):
//   DMA_B(i) -> STAGE_A(i) -> sync (drain B+ds_writes, convoy anchor)
//   -> LOAD_A(i+1) (flies under MFMA) -> MFMA 64/wave -> sync (drain A)
// ---------------------------------------------------------------------------
#define BM 256
#define BN 256
#define BK 64
#define KMAX (K_ - BK)                   // 960
#define NGEMM ((M_ / BM) * (N_ / BN))    // 128*2 = 256
#define NATTN 512                        // 64 rows each

__global__ __launch_bounds__(512, 2)
void gemm_attn(const unsigned short* __restrict__ Wbf,
               const float* __restrict__ bias,
               float* __restrict__ out,
               float* __restrict__ attn,
               const float* __restrict__ ctx,
               const float* __restrict__ outp,
               const int* __restrict__ jbuf) {
    const int bx = blockIdx.x;
    const int tid = threadIdx.x;

    __shared__ unsigned short As[BM * BK];   // 32 KB
    __shared__ unsigned short Bs[BN * BK];   // 32 KB

    if (bx >= NGEMM) {
        // ---------------- attn one-hot: 64 rows per block, 512 threads ----
        const int m0 = (bx - NGEMM) * 64;
        const int col  = tid & 255;            // f32x4 column (256 per row)
        const int half = tid >> 8;             // 0..1: row parity
        #pragma unroll 4
        for (int r = 0; r < 32; ++r) {
            const int row = m0 + r * 2 + half;
            const int j = jbuf[row];           // wave-uniform broadcast
            f32x4 v = {0.f, 0.f, 0.f, 0.f};
            if ((j >> 2) == col) v[j & 3] = 1.0f;
            __builtin_nontemporal_store(v, ((f32x4*)(attn + (size_t)row * S_)) + col);
        }
        return;
    }

    // ---------------- GEMM tile 256x256 ----------------
    const int lane = tid & 63;
    const int wave = tid >> 6;                   // 0..7
    const int wm = wave >> 1, wn = wave & 1;     // 4x2 waves -> 64x128 each
    const int l16 = lane & 15, quad = lane >> 4;

    // sibling-adjacent same-XCD map: bn-pair of each bm spaced 8 apart.
    const int xcd = bx & 7;
    const int bn  = (bx >> 3) & 1;               // 2 n-tiles of 256
    const int bm  = ((bx >> 4) << 3) | xcd;      // 128 m-tiles of 256
    const int mBase = bm * BM;
    const int nBase = bn * BN;

    // A staging: chunk c = it*512+tid, row = it*64 + (tid>>3), g = tid&7.
    const int g    = tid & 7;
    const int rsub = tid >> 3;                   // 0..63
    const int sw   = g ^ (rsub & 7);             // swizzle, it-invariant (64%8==0)
    const float* actx[4];
    const float* aout[4];
    const unsigned short* bSrc[4];
    #pragma unroll
    for (int it = 0; it < 4; ++it) {
        const int r = it * 64 + rsub;
        const int m = mBase + r;
        const int jm = jbuf[m];
        actx[it] = ctx + ((size_t)((m >> 10) * S_ + jm)) * D_ + g * 8;
        aout[it] = outp + (size_t)m * D_ - D_ + g * 8;      // add ko>=512
        // B: row&7 == rsub&7 -> source granule == sw (pre-swizzled, linear dest)
        bSrc[it] = Wbf + (size_t)(nBase + r) * K_ + sw * 8;
    }

    f32x4 acc[4][8] = {};
    f32x4 fa[4][2];

#define LOAD_A(KO) do {                                                        \
    const int _koa = (KO);                                                     \
    _Pragma("unroll")                                                          \
    for (int _it = 0; _it < 4; ++_it) {                                        \
        const float* _src = (_koa < D_) ? (actx[_it] + _koa) : (aout[_it] + _koa); \
        fa[_it][0] = ((const f32x4*)_src)[0];                                  \
        fa[_it][1] = ((const f32x4*)_src)[1];                                  \
    }                                                                          \
} while (0)

    // prologue: prefetch A(0); only iter-0's cvt sees full load latency.
    LOAD_A(0);

    for (int ko = 0; ko < K_; ko += BK) {
        // ---- 1. B(i) -> LDS DMA (4 x global_load_lds, in flight across cvt)
        #pragma unroll
        for (int it = 0; it < 4; ++it) {
            __builtin_amdgcn_global_load_lds(
                (const __attribute__((address_space(1))) void*)(bSrc[it] + ko),
                (__attribute__((address_space(3))) void*)(Bs + (it * 512 + tid) * 8),
                16, 0, 0);
        }
        // ---- 2. cvt + swizzled ds_write_b128 (fa prefetched last iter)
        #pragma unroll
        for (int it = 0; it < 4; ++it) {
            union { bf16x8 v; unsigned u[4]; } pk;
            pk.u[0] = cvt2bf(fa[it][0][0], fa[it][0][1]);
            pk.u[1] = cvt2bf(fa[it][0][2], fa[it][0][3]);
            pk.u[2] = cvt2bf(fa[it][1][0], fa[it][1][1]);
            pk.u[3] = cvt2bf(fa[it][1][2], fa[it][1][3]);
            *(bf16x8*)&As[(it * 512 + rsub * 8 + sw) * 8] = pk.v;
        }
        __syncthreads();                         // drain B DMA + ds_writes

        // ---- 3. prefetch A(i+1) into the same regs; flies under MFMA
        {
            const int ko2 = (ko + BK > KMAX) ? KMAX : ko + BK;   // clamped tail
            LOAD_A(ko2);
        }

        // ---- 4. MFMA phase: 2 K-steps of 32; 32 MFMA each (4mt x 8nt)
        #pragma unroll
        for (int ks = 0; ks < 2; ++ks) {
            bf16x8 af[4], bfr[8];
            const int q = ks * 4 + quad;
            #pragma unroll
            for (int mt = 0; mt < 4; ++mt) {
                const int r = wm * 64 + mt * 16 + l16;
                af[mt] = *(const bf16x8*)&As[(r * 8 + (q ^ (r & 7))) * 8];
            }
            #pragma unroll
            for (int nt = 0; nt < 8; ++nt) {
                const int rb = wn * 128 + nt * 16 + l16;
                bfr[nt] = *(const bf16x8*)&Bs[(rb * 8 + (q ^ (rb & 7))) * 8];
            }
            #pragma unroll
            for (int mt = 0; mt < 4; ++mt)
                #pragma unroll
                for (int nt = 0; nt < 8; ++nt)
                    acc[mt][nt] = __builtin_amdgcn_mfma_f32_16x16x32_bf16(
                        af[mt], bfr[nt], acc[mt][nt], 0, 0, 0);
        }
        __syncthreads();                         // drain A prefetch (mostly done)
    }

#undef LOAD_A

    // ---- epilogue: fast_tanh(acc + bias), fp32 NT store (streaming, no reuse)
    #pragma unroll
    for (int nt = 0; nt < 8; ++nt) {
        const int n = nBase + wn * 128 + nt * 16 + l16;
        const float bv = bias[n];
        #pragma unroll
        for (int mt = 0; mt < 4; ++mt) {
            #pragma unroll
            for (int r = 0; r < 4; ++r) {
                const int m = mBase + wm * 64 + mt * 16 + quad * 4 + r;
                const float val = fast_tanh(acc[mt][nt][r] + bv);
                __builtin_nontemporal_store(val, &out[(size_t)m * N_ + n]);
            }
        }
    }
}

// ---------------------------------------------------------------------------
extern "C" void kernel_launch(void* const* d_in, const int* in_sizes, int n_in,
                              void* d_out, int out_size, void* d_ws, size_t ws_size,
                              hipStream_t stream) {
    const int*   iv   = (const int*)d_in[0];    // input_var [B,T]
    const float* outp = (const float*)d_in[1];  // output   [B,T,D]
    const float* ctx  = (const float*)d_in[2];  // context  [B,S,D]
    // d_in[3] = di (unused by reference body)
    const float* W    = (const float*)d_in[4];  // [D, 2D]
    const float* bias = (const float*)d_in[5];  // [D]

    float* out  = (float*)d_out;                       // [B,T,D]
    float* attn = out + (size_t)M_ * N_;               // [B,T,S]

    // workspace layout: j[M_] int32 | Wbf[N_*K_] bf16   (~1.1 MB total)
    int* jbuf = (int*)d_ws;
    unsigned short* Wbf = (unsigned short*)((char*)d_ws + (size_t)M_ * 4);

    align_kernel<<<B_, 64, 0, stream>>>(iv, jbuf);
    pack_w<<<(N_ * K_ / 8) / 256, 256, 0, stream>>>(W, Wbf);
    gemm_attn<<<NGEMM + NATTN, 512, 0, stream>>>(Wbf, bias, out, attn, ctx, outp, jbuf);
}

// Round 11
// 328.194 us; speedup vs baseline: 1.1486x; 1.0001x over previous
//
#include <hip/hip_runtime.h>
#include <hip/hip_bf16.h>

// Problem constants (B,T,S,D = 32,1024,1024,512)
#define B_ 32
#define T_ 1024
#define S_ 1024
#define D_ 512
#define M_ (B_*T_)       // 32768 GEMM rows
#define N_ D_            // 512  GEMM cols
#define K_ (2*D_)        // 1024 GEMM reduction

typedef __attribute__((ext_vector_type(8))) short bf16x8;  // 8 bf16 = 4 VGPRs
typedef __attribute__((ext_vector_type(4))) float f32x4;

__device__ inline unsigned short f2bf(float x) {
    union { float f; unsigned u; } v; v.f = x;
    unsigned r = v.u + 0x7FFFu + ((v.u >> 16) & 1u);   // RNE
    return (unsigned short)(r >> 16);
}

// pack 2 f32 -> 2 bf16 (RNE), packed in 32 bits
__device__ inline unsigned cvt2bf(float lo, float hi) {
#if __has_builtin(__builtin_amdgcn_cvt_pk_bf16_f32)
    typedef __attribute__((ext_vector_type(2))) __bf16 bf2;
    union { bf2 v; unsigned u; } r;
    r.v = __builtin_amdgcn_cvt_pk_bf16_f32(lo, hi);
    return r.u;
#else
    return (unsigned)f2bf(lo) | ((unsigned)f2bf(hi) << 16);
#endif
}

// fast tanh: 1 - 2/(e^{2x}+1) via hw exp2 + rcp. rel err ~1e-7, exact sat at +-1.
__device__ inline float fast_tanh(float x) {
#if __has_builtin(__builtin_amdgcn_exp2f) && __has_builtin(__builtin_amdgcn_rcpf)
    const float e = __builtin_amdgcn_exp2f(x * 2.885390082f);   // e^{2x}
    const float r = __builtin_amdgcn_rcpf(e + 1.0f);
    return 1.0f - 2.0f * r;
#else
    return tanhf(x);
#endif
}

// ---------------------------------------------------------------------------
// Kernel 1: alignment scan -> jbuf.
// ---------------------------------------------------------------------------
__global__ void align_kernel(const int* __restrict__ iv, int* __restrict__ jbuf) {
    const int b = blockIdx.x;          // 32 blocks x 64 threads
    const int lane = threadIdx.x;      // 16 tokens per lane
    const int* row = iv + b * T_;
    int f[16];
    int local = 0;
    const int t0 = lane * 16;
    #pragma unroll
    for (int q = 0; q < 16; ++q) {
        const int t = t0 + q;
        const int tok = row[t];
        const int fl = (t > 0 && (tok == 1 || tok == 2)) ? 1 : 0;
        f[q] = fl;
        local += fl;
    }
    int incl = local;
    #pragma unroll
    for (int off = 1; off < 64; off <<= 1) {
        const int up = __shfl_up(incl, off, 64);
        if (lane >= off) incl += up;
    }
    int run = incl - local;            // exclusive prefix at this lane's first token
    #pragma unroll
    for (int q = 0; q < 16; ++q) {
        const int t = t0 + q;
        run += f[q];
        int j;
        if (t == 0) {
            j = 0;                     // attn[b,0,0] = 1 always
        } else {
            j = t - run - 1;
            if (j < 0) j += S_;        // torch negative-index wrap
        }
        jbuf[b * T_ + t] = j;
    }
}

// ---------------------------------------------------------------------------
// Kernel 2: W [512,1024] f32 -> bf16
// ---------------------------------------------------------------------------
__global__ void pack_w(const float* __restrict__ W, unsigned short* __restrict__ Wbf) {
    const int idx = blockIdx.x * blockDim.x + threadIdx.x;   // N_*K_/8 threads
    const f32x4 a = ((const f32x4*)W)[idx * 2];
    const f32x4 c = ((const f32x4*)W)[idx * 2 + 1];
    union { bf16x8 v; unsigned u[4]; } pk;
    pk.u[0] = cvt2bf(a[0], a[1]); pk.u[1] = cvt2bf(a[2], a[3]);
    pk.u[2] = cvt2bf(c[0], c[1]); pk.u[3] = cvt2bf(c[2], c[3]);
    *(bf16x8*)(Wbf + (size_t)idx * 8) = pk.v;
}

// ---------------------------------------------------------------------------
// Kernel 3: GEMM 256x256, grid = 256 blocks (1/CU, one generation).
//
// R16 = R15 with the attn one-hot writes FOLDED INTO THE GEMM EPILOGUE:
// each block NT-writes its own 128 attn rows (bn picks which half of the
// 256-row m-panel) before the tanh/out stores -> the previously SERIAL
// ~25-30us attn tail (1 block/CU meant attn blocks ran after gemm) now
// overlaps the tanh VALU work and runs fully parallel across 256 CUs.
// Safe: NT bypasses L2 (no working-set eviction); R8 isolated R7's traffic
// explosion to the counted-vmcnt loop, not attn placement.
//
// K-loop per iter (R14/R15 verbatim, proven):
//   DMA_B(i) -> STAGE_A(i) -> sync (drain B+ds_writes, convoy anchor)
//   -> LOAD_A(i+1) (flies under MFMA) -> MFMA 64/wave -> sync (drain A)
// ---------------------------------------------------------------------------
#define BM 256
#define BN 256
#define BK 64
#define KMAX (K_ - BK)                   // 960
#define NGEMM ((M_ / BM) * (N_ / BN))    // 128*2 = 256

__global__ __launch_bounds__(512, 2)
void gemm_attn(const unsigned short* __restrict__ Wbf,
               const float* __restrict__ bias,
               float* __restrict__ out,
               float* __restrict__ attn,
               const float* __restrict__ ctx,
               const float* __restrict__ outp,
               const int* __restrict__ jbuf) {
    const int bx = blockIdx.x;
    const int tid = threadIdx.x;

    __shared__ unsigned short As[BM * BK];   // 32 KB
    __shared__ unsigned short Bs[BN * BK];   // 32 KB

    // ---------------- GEMM tile 256x256 ----------------
    const int lane = tid & 63;
    const int wave = tid >> 6;                   // 0..7
    const int wm = wave >> 1, wn = wave & 1;     // 4x2 waves -> 64x128 each
    const int l16 = lane & 15, quad = lane >> 4;

    // sibling-adjacent same-XCD map: bn-pair of each bm spaced 8 apart.
    const int xcd = bx & 7;
    const int bn  = (bx >> 3) & 1;               // 2 n-tiles of 256
    const int bm  = ((bx >> 4) << 3) | xcd;      // 128 m-tiles of 256
    const int mBase = bm * BM;
    const int nBase = bn * BN;

    // A staging: chunk c = it*512+tid, row = it*64 + (tid>>3), g = tid&7.
    const int g    = tid & 7;
    const int rsub = tid >> 3;                   // 0..63
    const int sw   = g ^ (rsub & 7);             // swizzle, it-invariant (64%8==0)
    const float* actx[4];
    const float* aout[4];
    const unsigned short* bSrc[4];
    #pragma unroll
    for (int it = 0; it < 4; ++it) {
        const int r = it * 64 + rsub;
        const int m = mBase + r;
        const int jm = jbuf[m];
        actx[it] = ctx + ((size_t)((m >> 10) * S_ + jm)) * D_ + g * 8;
        aout[it] = outp + (size_t)m * D_ - D_ + g * 8;      // add ko>=512
        // B: row&7 == rsub&7 -> source granule == sw (pre-swizzled, linear dest)
        bSrc[it] = Wbf + (size_t)(nBase + r) * K_ + sw * 8;
    }

    f32x4 acc[4][8] = {};
    f32x4 fa[4][2];

#define LOAD_A(KO) do {                                                        \
    const int _koa = (KO);                                                     \
    _Pragma("unroll")                                                          \
    for (int _it = 0; _it < 4; ++_it) {                                        \
        const float* _src = (_koa < D_) ? (actx[_it] + _koa) : (aout[_it] + _koa); \
        fa[_it][0] = ((const f32x4*)_src)[0];                                  \
        fa[_it][1] = ((const f32x4*)_src)[1];                                  \
    }                                                                          \
} while (0)

    // prologue: prefetch A(0); only iter-0's cvt sees full load latency.
    LOAD_A(0);

    for (int ko = 0; ko < K_; ko += BK) {
        // ---- 1. B(i) -> LDS DMA (4 x global_load_lds, in flight across cvt)
        #pragma unroll
        for (int it = 0; it < 4; ++it) {
            __builtin_amdgcn_global_load_lds(
                (const __attribute__((address_space(1))) void*)(bSrc[it] + ko),
                (__attribute__((address_space(3))) void*)(Bs + (it * 512 + tid) * 8),
                16, 0, 0);
        }
        // ---- 2. cvt + swizzled ds_write_b128 (fa prefetched last iter)
        #pragma unroll
        for (int it = 0; it < 4; ++it) {
            union { bf16x8 v; unsigned u[4]; } pk;
            pk.u[0] = cvt2bf(fa[it][0][0], fa[it][0][1]);
            pk.u[1] = cvt2bf(fa[it][0][2], fa[it][0][3]);
            pk.u[2] = cvt2bf(fa[it][1][0], fa[it][1][1]);
            pk.u[3] = cvt2bf(fa[it][1][2], fa[it][1][3]);
            *(bf16x8*)&As[(it * 512 + rsub * 8 + sw) * 8] = pk.v;
        }
        __syncthreads();                         // drain B DMA + ds_writes

        // ---- 3. prefetch A(i+1) into the same regs; flies under MFMA
        {
            const int ko2 = (ko + BK > KMAX) ? KMAX : ko + BK;   // clamped tail
            LOAD_A(ko2);
        }

        // ---- 4. MFMA phase: 2 K-steps of 32; 32 MFMA each (4mt x 8nt)
        #pragma unroll
        for (int ks = 0; ks < 2; ++ks) {
            bf16x8 af[4], bfr[8];
            const int q = ks * 4 + quad;
            #pragma unroll
            for (int mt = 0; mt < 4; ++mt) {
                const int r = wm * 64 + mt * 16 + l16;
                af[mt] = *(const bf16x8*)&As[(r * 8 + (q ^ (r & 7))) * 8];
            }
            #pragma unroll
            for (int nt = 0; nt < 8; ++nt) {
                const int rb = wn * 128 + nt * 16 + l16;
                bfr[nt] = *(const bf16x8*)&Bs[(rb * 8 + (q ^ (rb & 7))) * 8];
            }
            #pragma unroll
            for (int mt = 0; mt < 4; ++mt)
                #pragma unroll
                for (int nt = 0; nt < 8; ++nt)
                    acc[mt][nt] = __builtin_amdgcn_mfma_f32_16x16x32_bf16(
                        af[mt], bfr[nt], acc[mt][nt], 0, 0, 0);
        }
        __syncthreads();                         // drain A prefetch (mostly done)
    }

#undef LOAD_A

    // ---- epilogue part 1: attn one-hot, 128 rows per block (bn picks half
    // of the 256-row m-panel). NT fire-and-forget; flies under the tanh VALU.
    {
        const int aBase = mBase + bn * 128;
        const int col  = tid & 255;            // f32x4 column (256 per row)
        const int half = tid >> 8;             // 0..1: row parity
        #pragma unroll 4
        for (int r = 0; r < 64; ++r) {
            const int row = aBase + r * 2 + half;
            const int j = jbuf[row];           // wave-uniform broadcast
            f32x4 v = {0.f, 0.f, 0.f, 0.f};
            if ((j >> 2) == col) v[j & 3] = 1.0f;
            __builtin_nontemporal_store(v, ((f32x4*)(attn + (size_t)row * S_)) + col);
        }
    }

    // ---- epilogue part 2: fast_tanh(acc + bias), fp32 NT store
    #pragma unroll
    for (int nt = 0; nt < 8; ++nt) {
        const int n = nBase + wn * 128 + nt * 16 + l16;
        const float bv = bias[n];
        #pragma unroll
        for (int mt = 0; mt < 4; ++mt) {
            #pragma unroll
            for (int r = 0; r < 4; ++r) {
                const int m = mBase + wm * 64 + mt * 16 + quad * 4 + r;
                const float val = fast_tanh(acc[mt][nt][r] + bv);
                __builtin_nontemporal_store(val, &out[(size_t)m * N_ + n]);
            }
        }
    }
}

// ---------------------------------------------------------------------------
extern "C" void kernel_launch(void* const* d_in, const int* in_sizes, int n_in,
                              void* d_out, int out_size, void* d_ws, size_t ws_size,
                              hipStream_t stream) {
    const int*   iv   = (const int*)d_in[0];    // input_var [B,T]
    const float* outp = (const float*)d_in[1];  // output   [B,T,D]
    const float* ctx  = (const float*)d_in[2];  // context  [B,S,D]
    // d_in[3] = di (unused by reference body)
    const float* W    = (const float*)d_in[4];  // [D, 2D]
    const float* bias = (const float*)d_in[5];  // [D]

    float* out  = (float*)d_out;                       // [B,T,D]
    float* attn = out + (size_t)M_ * N_;               // [B,T,S]

    // workspace layout: j[M_] int32 | Wbf[N_*K_] bf16   (~1.1 MB total)
    int* jbuf = (int*)d_ws;
    unsigned short* Wbf = (unsigned short*)((char*)d_ws + (size_t)M_ * 4);

    align_kernel<<<B_, 64, 0, stream>>>(iv, jbuf);
    pack_w<<<(N_ * K_ / 8) / 256, 256, 0, stream>>>(W, Wbf);
    gemm_attn<<<NGEMM, 512, 0, stream>>>(Wbf, bias, out, attn, ctx, outp, jbuf);
}